// Round 1
// baseline (1029.785 us; speedup 1.0000x reference)
//
#include <hip/hip_runtime.h>

// MoE top-2, B=4 T=2048 D=1024 F=2816 E=8, fp32 in/out, bf16 MFMA internals.
constexpr int TOKENS = 8192;   // B*T
constexpr int D = 1024;
constexpr int F = 2816;
constexpr int E = 8;

typedef __bf16 bf16x8 __attribute__((ext_vector_type(8)));
typedef float  f32x4  __attribute__((ext_vector_type(4)));

__device__ __forceinline__ unsigned short f32_bf16(float f) {
  union { float f; unsigned u; } v; v.f = f;
  unsigned u = v.u;
  return (unsigned short)((u + 0x7FFFu + ((u >> 16) & 1u)) >> 16);  // RNE
}

// 16B-wide direct global->LDS. Dest must be wave-uniform base; HW adds lane*16.
__device__ __forceinline__ void gload_lds16(const void* g, void* l) {
  __builtin_amdgcn_global_load_lds(
      (const __attribute__((address_space(1))) void*)g,
      (__attribute__((address_space(3))) void*)l, 16, 0, 0);
}

// ---------------- weight convert + transpose: src fp32 [E][R][C] -> dst bf16 [E][C][R]
__global__ __launch_bounds__(256) void k_transpose(
    const float* __restrict__ src, unsigned short* __restrict__ dst, int R, int C) {
  __shared__ unsigned short tile[64][65];   // +1 pad: transposed read ~conflict-free
  const int e = blockIdx.z;
  const int r0 = blockIdx.y * 64, c0 = blockIdx.x * 64;
  const int tid = threadIdx.x;
  const int lr = tid >> 6, lc = tid & 63;
  const float* sp = src + ((size_t)e * R + r0) * C + c0;
  #pragma unroll
  for (int q = 0; q < 16; ++q)
    tile[q*4 + lr][lc] = f32_bf16(sp[(size_t)(q*4 + lr) * C + lc]);
  __syncthreads();
  unsigned short* dp = dst + ((size_t)e * C + c0) * R + r0;
  #pragma unroll
  for (int q = 0; q < 16; ++q)
    dp[(size_t)(q*4 + lr) * R + lc] = tile[lc][q*4 + lr];
}

// ---------------- router: scores, top-2, dispatch lists, x->bf16
__global__ __launch_bounds__(256) void k_router(
    const float* __restrict__ x, const float* __restrict__ rw,
    unsigned short* __restrict__ xb,
    int* __restrict__ ltok,
    int* __restrict__ pcode, float* __restrict__ pw,
    int* __restrict__ cnt) {
  const int t = blockIdx.x * 4 + (threadIdx.x >> 6);  // wave per token
  const int l = threadIdx.x & 63;
  const float* xr = x + (size_t)t * D;
  float s0=0,s1=0,s2=0,s3=0,s4=0,s5=0,s6=0,s7=0;
  #pragma unroll
  for (int i = 0; i < D/64; ++i) {
    int d = i*64 + l;
    float xv = xr[d];
    xb[(size_t)t*D + d] = f32_bf16(xv);
    const float4* rp = (const float4*)(rw + d*8);   // router_w is [D][8]
    float4 a = rp[0], b = rp[1];
    s0 += xv*a.x; s1 += xv*a.y; s2 += xv*a.z; s3 += xv*a.w;
    s4 += xv*b.x; s5 += xv*b.y; s6 += xv*b.z; s7 += xv*b.w;
  }
  float s[8] = {s0,s1,s2,s3,s4,s5,s6,s7};
  #pragma unroll
  for (int e = 0; e < 8; ++e) {
    #pragma unroll
    for (int m = 32; m > 0; m >>= 1) s[e] += __shfl_xor(s[e], m, 64);
  }
  if (l == 0) {
    // top-2 with lowest-index tie-break (matches lax.top_k)
    int i0 = 0; float b0 = s[0];
    #pragma unroll
    for (int e = 1; e < 8; ++e) if (s[e] > b0) { b0 = s[e]; i0 = e; }
    int i1 = (i0 == 0) ? 1 : 0; float b1 = s[i1];
    #pragma unroll
    for (int e = 0; e < 8; ++e) if (e != i0 && s[e] > b1) { b1 = s[e]; i1 = e; }
    // normalized top-2 softmax: full-softmax denominator cancels
    float w0 = 1.f / (1.f + __expf(b1 - b0));
    float w1 = 1.f - w0;
    int p0 = atomicAdd(&cnt[i0], 1);
    ltok[i0*TOKENS + p0] = t;
    int p1 = atomicAdd(&cnt[i1], 1);
    ltok[i1*TOKENS + p1] = t;
    pcode[t*2]   = (i0 << 13) | p0;  pw[t*2]   = w0;
    pcode[t*2+1] = (i1 << 13) | p1;  pw[t*2+1] = w1;
  }
}

__global__ void k_scan(const int* __restrict__ cnt, int* __restrict__ offs) {
  if (threadIdx.x == 0) {
    int a = 0;
    for (int e = 0; e < E; ++e) { offs[e] = a; a += cnt[e]; }
    offs[E] = a;
  }
}

// ---------------- pass1: grouped GEMM gate+up + SiLU  -> act bf16 [2*TOKENS][F]
// A = gathered xb rows [n_e x D]; B = wg/wu transposed [E][F][D].
// 128x128 tile, BK=64, 4 waves (2x2 of 64x64). LDS XOR-(row&7) swizzle via
// pre-swizzled global source (global_load_lds writes linearly).
__global__ __launch_bounds__(256) void k_pass1(
    const unsigned short* __restrict__ xb,
    const unsigned short* __restrict__ wg,
    const unsigned short* __restrict__ wu,
    const int* __restrict__ ltok,
    const int* __restrict__ cnt,
    const int* __restrict__ offs,
    unsigned short* __restrict__ act) {
  const int e = blockIdx.z;
  const int n = cnt[e];
  const int rt = blockIdx.y;
  if (rt * 128 >= n) return;
  const int ft = blockIdx.x;
  __shared__ unsigned short lA[128*64];
  __shared__ unsigned short lG[128*64];
  __shared__ unsigned short lU[128*64];
  const int tid = threadIdx.x, l = tid & 63, w = tid >> 6;
  const int wr = (w >> 1) * 64, wc = (w & 1) * 64;
  const int sl = (l & 7) ^ ((l >> 3) & 7);   // logical 16B slot this lane fetches
  int tok[4], brow[4];
  #pragma unroll
  for (int q = 0; q < 4; ++q) {
    int r = (w*4 + q)*8 + (l >> 3);          // LDS row this lane's 16B lands in
    brow[q] = r;
    int rg = rt*128 + r;
    tok[q] = ltok[e*TOKENS + (rg < n ? rg : 0)];
  }
  f32x4 aG[4][4] = {}; f32x4 aU[4][4] = {};
  for (int k0 = 0; k0 < D; k0 += 64) {
    #pragma unroll
    for (int q = 0; q < 4; ++q) {
      const int dst = (w*4 + q) * 512;       // wave-uniform LDS base (elems)
      gload_lds16(xb + (size_t)tok[q]*D + k0 + sl*8, &lA[dst]);
      size_t wo = ((size_t)e*F + ft*128 + brow[q]) * D + k0 + sl*8;
      gload_lds16(wg + wo, &lG[dst]);
      gload_lds16(wu + wo, &lU[dst]);
    }
    __syncthreads();
    #pragma unroll
    for (int ks = 0; ks < 2; ++ks) {
      bf16x8 af[4];
      #pragma unroll
      for (int mi = 0; mi < 4; ++mi) {
        int row = wr + mi*16 + (l & 15);
        int sp  = (ks*4 + (l >> 4)) ^ (row & 7);
        af[mi] = *(const bf16x8*)&lA[row*64 + sp*8];
      }
      #pragma unroll
      for (int ni = 0; ni < 4; ++ni) {
        int fr = wc + ni*16 + (l & 15);
        int sp = (ks*4 + (l >> 4)) ^ (fr & 7);
        bf16x8 bg = *(const bf16x8*)&lG[fr*64 + sp*8];
        bf16x8 bu = *(const bf16x8*)&lU[fr*64 + sp*8];
        #pragma unroll
        for (int mi = 0; mi < 4; ++mi) {
          aG[mi][ni] = __builtin_amdgcn_mfma_f32_16x16x32_bf16(af[mi], bg, aG[mi][ni], 0, 0, 0);
          aU[mi][ni] = __builtin_amdgcn_mfma_f32_16x16x32_bf16(af[mi], bu, aU[mi][ni], 0, 0, 0);
        }
      }
    }
    __syncthreads();
  }
  #pragma unroll
  for (int mi = 0; mi < 4; ++mi) {
    #pragma unroll
    for (int j = 0; j < 4; ++j) {
      int rl = wr + mi*16 + (l >> 4)*4 + j;  // C/D: row=(lane>>4)*4+reg, col=lane&15
      int rg = rt*128 + rl;
      if (rg < n) {
        unsigned short* ap = act + ((size_t)offs[e] + rg) * F + ft*128 + wc + (l & 15);
        #pragma unroll
        for (int ni = 0; ni < 4; ++ni) {
          float g = aG[mi][ni][j], u = aU[mi][ni][j];
          float sv = g / (1.f + __expf(-g)) * u;   // silu(g)*u
          ap[ni*16] = f32_bf16(sv);
        }
      }
    }
  }
}

// ---------------- pass2: act [rows][F] x down^T [E][D][F] -> eo fp32 [rows][D]
__global__ __launch_bounds__(256) void k_pass2(
    const unsigned short* __restrict__ act,
    const unsigned short* __restrict__ wdt,
    const int* __restrict__ cnt,
    const int* __restrict__ offs,
    float* __restrict__ eo) {
  const int e = blockIdx.z;
  const int n = cnt[e];
  const int rt = blockIdx.y;
  if (rt * 128 >= n) return;
  const int dt = blockIdx.x;
  __shared__ unsigned short lA[128*64];
  __shared__ unsigned short lB[128*64];
  const int tid = threadIdx.x, l = tid & 63, w = tid >> 6;
  const int wr = (w >> 1) * 64, wc = (w & 1) * 64;
  const int sl = (l & 7) ^ ((l >> 3) & 7);
  size_t arow[4]; int brow[4];
  #pragma unroll
  for (int q = 0; q < 4; ++q) {
    int r = (w*4 + q)*8 + (l >> 3);
    brow[q] = r;
    int rg = rt*128 + r;
    arow[q] = (size_t)offs[e] + (rg < n ? rg : 0);
  }
  f32x4 acc[4][4] = {};
  for (int k0 = 0; k0 < F; k0 += 64) {
    #pragma unroll
    for (int q = 0; q < 4; ++q) {
      const int dst = (w*4 + q) * 512;
      gload_lds16(act + arow[q]*F + k0 + sl*8, &lA[dst]);
      gload_lds16(wdt + ((size_t)e*D + dt*128 + brow[q]) * F + k0 + sl*8, &lB[dst]);
    }
    __syncthreads();
    #pragma unroll
    for (int ks = 0; ks < 2; ++ks) {
      bf16x8 af[4];
      #pragma unroll
      for (int mi = 0; mi < 4; ++mi) {
        int row = wr + mi*16 + (l & 15);
        int sp  = (ks*4 + (l >> 4)) ^ (row & 7);
        af[mi] = *(const bf16x8*)&lA[row*64 + sp*8];
      }
      #pragma unroll
      for (int ni = 0; ni < 4; ++ni) {
        int dr = wc + ni*16 + (l & 15);
        int sp = (ks*4 + (l >> 4)) ^ (dr & 7);
        bf16x8 bd = *(const bf16x8*)&lB[dr*64 + sp*8];
        #pragma unroll
        for (int mi = 0; mi < 4; ++mi)
          acc[mi][ni] = __builtin_amdgcn_mfma_f32_16x16x32_bf16(af[mi], bd, acc[mi][ni], 0, 0, 0);
      }
    }
    __syncthreads();
  }
  #pragma unroll
  for (int mi = 0; mi < 4; ++mi) {
    #pragma unroll
    for (int j = 0; j < 4; ++j) {
      int rl = wr + mi*16 + (l >> 4)*4 + j;
      int rg = rt*128 + rl;
      if (rg < n) {
        float* op = eo + ((size_t)offs[e] + rg) * D + dt*128 + wc + (l & 15);
        #pragma unroll
        for (int ni = 0; ni < 4; ++ni) op[ni*16] = acc[mi][ni][j];
      }
    }
  }
}

// ---------------- combine: out[t] = w0*eo[row0] + w1*eo[row1]
__global__ __launch_bounds__(256) void k_combine(
    const float* __restrict__ eo, const int* __restrict__ pcode,
    const float* __restrict__ pw, const int* __restrict__ offs,
    float* __restrict__ out) {
  const int t = blockIdx.x;
  const int d4 = threadIdx.x * 4;
  int c0 = pcode[t*2], c1 = pcode[t*2+1];
  float w0 = pw[t*2], w1 = pw[t*2+1];
  size_t r0 = (size_t)offs[c0 >> 13] + (c0 & 8191);
  size_t r1 = (size_t)offs[c1 >> 13] + (c1 & 8191);
  const float4 a = *(const float4*)&eo[r0*D + d4];
  const float4 b = *(const float4*)&eo[r1*D + d4];
  float4 o;
  o.x = w0*a.x + w1*b.x; o.y = w0*a.y + w1*b.y;
  o.z = w0*a.z + w1*b.z; o.w = w0*a.w + w1*b.w;
  *(float4*)&out[(size_t)t*D + d4] = o;
}

extern "C" void kernel_launch(void* const* d_in, const int* in_sizes, int n_in,
                              void* d_out, int out_size, void* d_ws, size_t ws_size,
                              hipStream_t stream) {
  const float* x  = (const float*)d_in[0];
  const float* rw = (const float*)d_in[1];
  const float* gp = (const float*)d_in[2];
  const float* up = (const float*)d_in[3];
  const float* dp = (const float*)d_in[4];
  float* out = (float*)d_out;
  char* ws = (char*)d_ws;
  size_t off = 0;
  auto take = [&](size_t b) { char* p = ws + off; off += (b + 255) & ~(size_t)255; return p; };
  unsigned short* xb  = (unsigned short*)take((size_t)TOKENS * D * 2);        // 16.8 MB
  unsigned short* wg  = (unsigned short*)take((size_t)E * F * D * 2);         // 46.1 MB
  unsigned short* wu  = (unsigned short*)take((size_t)E * F * D * 2);         // 46.1 MB
  unsigned short* wdt = (unsigned short*)take((size_t)E * D * F * 2);         // 46.1 MB
  unsigned short* act = (unsigned short*)take((size_t)2 * TOKENS * F * 2);    // 92.3 MB
  int*   ltok  = (int*)take((size_t)E * TOKENS * 4);
  int*   pcode = (int*)take((size_t)TOKENS * 2 * 4);
  float* pwv   = (float*)take((size_t)TOKENS * 2 * 4);
  int*   cnt   = (int*)take(64);
  int*   offs  = (int*)take(64);
  // eo (67 MB fp32 [2*TOKENS][D]) aliases wg/wu: dead after pass1, re-built each call.
  float* eo = (float*)wg;

  hipMemsetAsync(cnt, 0, 8 * sizeof(int), stream);
  k_transpose<<<dim3(F/64, D/64, E), 256, 0, stream>>>(gp, wg, D, F);   // -> [E][F][D]
  k_transpose<<<dim3(F/64, D/64, E), 256, 0, stream>>>(up, wu, D, F);
  k_transpose<<<dim3(D/64, F/64, E), 256, 0, stream>>>(dp, wdt, F, D);  // -> [E][D][F]
  k_router<<<dim3(TOKENS/4), 256, 0, stream>>>(x, rw, xb, ltok, pcode, pwv, cnt);
  k_scan<<<1, 64, 0, stream>>>(cnt, offs);
  k_pass1<<<dim3(F/128, TOKENS/128, E), 256, 0, stream>>>(xb, wg, wu, ltok, cnt, offs, act);
  k_pass2<<<dim3(D/128, TOKENS/128, E), 256, 0, stream>>>(act, wdt, cnt, offs, eo);
  k_combine<<<dim3(TOKENS), 256, 0, stream>>>(eo, pcode, pwv, offs, out);
}

// Round 2
// 875.525 us; speedup vs baseline: 1.1762x; 1.1762x over previous
//
#include <hip/hip_runtime.h>

// MoE top-2, B=4 T=2048 D=1024 F=2816 E=8, fp32 in/out, bf16 MFMA internals.
// R1: 2-phase dbuf GEMMs (T3-minimum recipe), fused wgu, weighted pass2 epilogue.
constexpr int TOKENS = 8192;   // B*T
constexpr int D = 1024;
constexpr int F = 2816;
constexpr int E = 8;
constexpr int NGU = 2 * F;     // fused gate/up rows: r = (f>>4)*32 + (f&15) + 16*is_up

typedef __bf16 bf16x8 __attribute__((ext_vector_type(8)));
typedef float  f32x4  __attribute__((ext_vector_type(4)));

__device__ __forceinline__ unsigned short f32_bf16(float f) {
  union { float f; unsigned u; } v; v.f = f;
  unsigned u = v.u;
  return (unsigned short)((u + 0x7FFFu + ((u >> 16) & 1u)) >> 16);  // RNE
}

__device__ __forceinline__ void gload_lds16(const void* g, void* l) {
  __builtin_amdgcn_global_load_lds(
      (const __attribute__((address_space(1))) void*)g,
      (__attribute__((address_space(3))) void*)l, 16, 0, 0);
}

// ---------------- gate+up convert/transpose -> wgu bf16 [E][2F][D] interleaved
__global__ __launch_bounds__(256) void k_transpose_gu(
    const float* __restrict__ g, const float* __restrict__ u,
    unsigned short* __restrict__ wgu) {
  __shared__ unsigned short tile[64][65];
  const int e = blockIdx.z;
  const int d0 = blockIdx.y * 64, f0 = blockIdx.x * 64;
  const int lr = threadIdx.x >> 6, lc = threadIdx.x & 63;
  for (int half = 0; half < 2; ++half) {
    const float* src = (half ? u : g) + ((size_t)e * D + d0) * F + f0;
    if (half) __syncthreads();
    #pragma unroll
    for (int q = 0; q < 16; ++q)
      tile[lc][q*4 + lr] = f32_bf16(src[(size_t)(q*4 + lr) * F + lc]);  // tile[f][d]
    __syncthreads();
    #pragma unroll
    for (int q = 0; q < 16; ++q) {
      int fi = q*4 + lr, fg = f0 + fi;
      int r = (fg >> 4) * 32 + (fg & 15) + half * 16;
      wgu[((size_t)e * NGU + r) * D + d0 + lc] = tile[fi][lc];
    }
  }
}

// ---------------- down convert/transpose: [E][F][D] -> wdt [E][D][F]
__global__ __launch_bounds__(256) void k_transpose(
    const float* __restrict__ src, unsigned short* __restrict__ dst, int R, int C) {
  __shared__ unsigned short tile[64][65];
  const int e = blockIdx.z;
  const int r0 = blockIdx.y * 64, c0 = blockIdx.x * 64;
  const int lr = threadIdx.x >> 6, lc = threadIdx.x & 63;
  const float* sp = src + ((size_t)e * R + r0) * C + c0;
  #pragma unroll
  for (int q = 0; q < 16; ++q)
    tile[q*4 + lr][lc] = f32_bf16(sp[(size_t)(q*4 + lr) * C + lc]);
  __syncthreads();
  unsigned short* dp = dst + ((size_t)e * C + c0) * R + r0;
  #pragma unroll
  for (int q = 0; q < 16; ++q)
    dp[(size_t)(q*4 + lr) * R + lc] = tile[lc][q*4 + lr];
}

// ---------------- router: scores, top-2, dispatch lists, x->bf16
__global__ __launch_bounds__(256) void k_router(
    const float* __restrict__ x, const float* __restrict__ rw,
    unsigned short* __restrict__ xb,
    unsigned short* __restrict__ ltok,
    float* __restrict__ lw,
    int* __restrict__ pcode,
    int* __restrict__ cnt) {
  const int t = blockIdx.x * 4 + (threadIdx.x >> 6);  // wave per token
  const int l = threadIdx.x & 63;
  const float* xr = x + (size_t)t * D;
  float s0=0,s1=0,s2=0,s3=0,s4=0,s5=0,s6=0,s7=0;
  #pragma unroll
  for (int i = 0; i < D/64; ++i) {
    int d = i*64 + l;
    float xv = xr[d];
    xb[(size_t)t*D + d] = f32_bf16(xv);
    const float4* rp = (const float4*)(rw + d*8);
    float4 a = rp[0], b = rp[1];
    s0 += xv*a.x; s1 += xv*a.y; s2 += xv*a.z; s3 += xv*a.w;
    s4 += xv*b.x; s5 += xv*b.y; s6 += xv*b.z; s7 += xv*b.w;
  }
  float s[8] = {s0,s1,s2,s3,s4,s5,s6,s7};
  #pragma unroll
  for (int e = 0; e < 8; ++e) {
    #pragma unroll
    for (int m = 32; m > 0; m >>= 1) s[e] += __shfl_xor(s[e], m, 64);
  }
  if (l == 0) {
    int i0 = 0; float b0 = s[0];
    #pragma unroll
    for (int e = 1; e < 8; ++e) if (s[e] > b0) { b0 = s[e]; i0 = e; }
    int i1 = (i0 == 0) ? 1 : 0; float b1 = s[i1];
    #pragma unroll
    for (int e = 0; e < 8; ++e) if (e != i0 && s[e] > b1) { b1 = s[e]; i1 = e; }
    float w0 = 1.f / (1.f + __expf(b1 - b0));
    float w1 = 1.f - w0;
    int p0 = atomicAdd(&cnt[i0], 1);
    ltok[i0*TOKENS + p0] = (unsigned short)t;
    lw[i0*TOKENS + p0] = w0;
    int p1 = atomicAdd(&cnt[i1], 1);
    ltok[i1*TOKENS + p1] = (unsigned short)t;
    lw[i1*TOKENS + p1] = w1;
    pcode[t*2]   = (i0 << 13) | p0;
    pcode[t*2+1] = (i1 << 13) | p1;
  }
}

__global__ void k_scan(const int* __restrict__ cnt, int* __restrict__ offs) {
  if (threadIdx.x == 0) {
    int a = 0;
    for (int e = 0; e < E; ++e) { offs[e] = a; a += cnt[e]; }
    offs[E] = a;
  }
}

// ---------------- pass1: A[n x 1024] x wgu[5632 x 1024]^T, 256x256 tile, BK=64,
// 8 waves (2x4), 2-phase dbuf (128 KB dynamic LDS), SiLU epilogue -> act bf16.
__global__ __launch_bounds__(512, 2) void k_pass1(
    const unsigned short* __restrict__ xb,
    const unsigned short* __restrict__ wgu,
    const unsigned short* __restrict__ ltok,
    const int* __restrict__ cnt,
    const int* __restrict__ offs,
    unsigned short* __restrict__ act) {
  const int e = blockIdx.z;
  const int n = cnt[e];
  const int rt = blockIdx.y;
  if (rt * 256 >= n) return;
  const int ft = blockIdx.x;
  extern __shared__ unsigned short smem[];   // [2][A 16384 | B 16384] elems
  const int tid = threadIdx.x, l = tid & 63, w = tid >> 6;
  const int wm = w >> 2, wn = w & 3;
  const int sl = (l & 7) ^ (l >> 3);         // swizzled 16B slot (row&7 == l>>3)
  size_t baseA[4], baseB[4];
  int dst[4];
  #pragma unroll
  for (int q = 0; q < 4; ++q) {
    int r = w*32 + q*8 + (l >> 3);
    int rg = rt*256 + r;
    int tok = ltok[e*TOKENS + (rg < n ? rg : 0)];
    baseA[q] = (size_t)tok * D + sl*8;
    baseB[q] = ((size_t)e * NGU + ft*256 + r) * D + sl*8;
    dst[q] = (w*4 + q) * 512;
  }
  f32x4 acc[8][4] = {};

  #define P1_STAGE(buf, k0) do { \
    _Pragma("unroll") \
    for (int q = 0; q < 4; ++q) { \
      gload_lds16(xb  + baseA[q] + (k0), &smem[(buf)*32768 + dst[q]]); \
      gload_lds16(wgu + baseB[q] + (k0), &smem[(buf)*32768 + 16384 + dst[q]]); \
    } } while (0)

  P1_STAGE(0, 0);
  __syncthreads();
  for (int t = 0; t < 16; ++t) {
    if (t < 15) P1_STAGE((t & 1) ^ 1, (t + 1) * 64);   // prefetch next tile
    const unsigned short* lA = &smem[(t & 1) * 32768];
    const unsigned short* lB = lA + 16384;
    bf16x8 bfr[4][2];
    #pragma unroll
    for (int nn = 0; nn < 4; ++nn) {
      int row = wn*64 + nn*16 + (l & 15);
      #pragma unroll
      for (int kk = 0; kk < 2; ++kk) {
        int sp = (kk*4 + (l >> 4)) ^ (row & 7);
        bfr[nn][kk] = *(const bf16x8*)&lB[row*64 + sp*8];
      }
    }
    __builtin_amdgcn_s_setprio(1);
    #pragma unroll
    for (int m = 0; m < 8; ++m) {
      int row = wm*128 + m*16 + (l & 15);
      int sp0 = ((l >> 4)    ) ^ (row & 7);
      int sp1 = ((l >> 4) + 4) ^ (row & 7);
      bf16x8 a0 = *(const bf16x8*)&lA[row*64 + sp0*8];
      bf16x8 a1 = *(const bf16x8*)&lA[row*64 + sp1*8];
      #pragma unroll
      for (int nn = 0; nn < 4; ++nn) {
        acc[m][nn] = __builtin_amdgcn_mfma_f32_16x16x32_bf16(a0, bfr[nn][0], acc[m][nn], 0, 0, 0);
        acc[m][nn] = __builtin_amdgcn_mfma_f32_16x16x32_bf16(a1, bfr[nn][1], acc[m][nn], 0, 0, 0);
      }
    }
    __builtin_amdgcn_s_setprio(0);
    __syncthreads();   // drains vmcnt(0): prefetch landed, overlapped with MFMA
  }
  #undef P1_STAGE
  // epilogue: fragments (0,1)=(gate,up)@fb0, (2,3)=(gate,up)@fb0+1
  const int fb0 = ft*8 + wn*2;
  #pragma unroll
  for (int m = 0; m < 8; ++m) {
    #pragma unroll
    for (int j = 0; j < 4; ++j) {
      int rl = wm*128 + m*16 + (l >> 4)*4 + j;
      int rg = rt*256 + rl;
      if (rg < n) {
        size_t rowo = ((size_t)offs[e] + rg) * F;
        #pragma unroll
        for (int p = 0; p < 2; ++p) {
          float g = acc[m][2*p][j], u = acc[m][2*p+1][j];
          float sv = g / (1.f + __expf(-g)) * u;
          act[rowo + (size_t)(fb0 + p)*16 + (l & 15)] = f32_bf16(sv);
        }
      }
    }
  }
}

// ---------------- pass2: act[n x 2816] x wdt[1024 x 2816]^T, 128x128, BK=64,
// 4 waves (2x2), 2-phase dbuf (64 KB static, 2 blocks/CU), weight in epilogue.
__global__ __launch_bounds__(256, 2) void k_pass2(
    const unsigned short* __restrict__ act,
    const unsigned short* __restrict__ wdt,
    const float* __restrict__ lw,
    const int* __restrict__ cnt,
    const int* __restrict__ offs,
    float* __restrict__ eo) {
  const int e = blockIdx.z;
  const int n = cnt[e];
  const int rt = blockIdx.y;
  if (rt * 128 >= n) return;
  const int dt = blockIdx.x;
  __shared__ unsigned short smem[2][2][8192];  // [buf][A|B][128*64]
  const int tid = threadIdx.x, l = tid & 63, w = tid >> 6;
  const int wr = (w >> 1) * 64, wc = (w & 1) * 64;
  const int sl = (l & 7) ^ (l >> 3);
  size_t baseA[4], baseB[4];
  int dst[4];
  #pragma unroll
  for (int q = 0; q < 4; ++q) {
    int r = w*32 + q*8 + (l >> 3);
    int rg = rt*128 + r;
    size_t arow = (size_t)offs[e] + (rg < n ? rg : 0);
    baseA[q] = arow * F + sl*8;
    baseB[q] = ((size_t)e * D + dt*128 + r) * F + sl*8;
    dst[q] = (w*4 + q) * 512;
  }
  f32x4 acc[4][4] = {};

  #define P2_STAGE(buf, k0) do { \
    _Pragma("unroll") \
    for (int q = 0; q < 4; ++q) { \
      gload_lds16(act + baseA[q] + (k0), &smem[buf][0][dst[q]]); \
      gload_lds16(wdt + baseB[q] + (k0), &smem[buf][1][dst[q]]); \
    } } while (0)

  P2_STAGE(0, 0);
  __syncthreads();
  for (int t = 0; t < 44; ++t) {
    if (t < 43) P2_STAGE((t & 1) ^ 1, (t + 1) * 64);
    const unsigned short* lA = smem[t & 1][0];
    const unsigned short* lB = smem[t & 1][1];
    bf16x8 bfr[4][2];
    #pragma unroll
    for (int nn = 0; nn < 4; ++nn) {
      int row = wc + nn*16 + (l & 15);
      #pragma unroll
      for (int kk = 0; kk < 2; ++kk) {
        int sp = (kk*4 + (l >> 4)) ^ (row & 7);
        bfr[nn][kk] = *(const bf16x8*)&lB[row*64 + sp*8];
      }
    }
    __builtin_amdgcn_s_setprio(1);
    #pragma unroll
    for (int m = 0; m < 4; ++m) {
      int row = wr + m*16 + (l & 15);
      int sp0 = ((l >> 4)    ) ^ (row & 7);
      int sp1 = ((l >> 4) + 4) ^ (row & 7);
      bf16x8 a0 = *(const bf16x8*)&lA[row*64 + sp0*8];
      bf16x8 a1 = *(const bf16x8*)&lA[row*64 + sp1*8];
      #pragma unroll
      for (int nn = 0; nn < 4; ++nn) {
        acc[m][nn] = __builtin_amdgcn_mfma_f32_16x16x32_bf16(a0, bfr[nn][0], acc[m][nn], 0, 0, 0);
        acc[m][nn] = __builtin_amdgcn_mfma_f32_16x16x32_bf16(a1, bfr[nn][1], acc[m][nn], 0, 0, 0);
      }
    }
    __builtin_amdgcn_s_setprio(0);
    __syncthreads();
  }
  #undef P2_STAGE
  #pragma unroll
  for (int m = 0; m < 4; ++m) {
    #pragma unroll
    for (int j = 0; j < 4; ++j) {
      int rl = wr + m*16 + (l >> 4)*4 + j;
      int rg = rt*128 + rl;
      if (rg < n) {
        float wrt = lw[e*TOKENS + rg];
        float* op = eo + ((size_t)offs[e] + rg) * D + dt*128 + wc + (l & 15);
        #pragma unroll
        for (int nn = 0; nn < 4; ++nn) op[nn*16] = acc[m][nn][j] * wrt;
      }
    }
  }
}

// ---------------- combine: out[t] = eo[row0] + eo[row1]  (weights pre-applied)
__global__ __launch_bounds__(256) void k_combine(
    const float* __restrict__ eo, const int* __restrict__ pcode,
    const int* __restrict__ offs, float* __restrict__ out) {
  const int t = blockIdx.x;
  const int d4 = threadIdx.x * 4;
  int c0 = pcode[t*2], c1 = pcode[t*2+1];
  size_t r0 = (size_t)offs[c0 >> 13] + (c0 & 8191);
  size_t r1 = (size_t)offs[c1 >> 13] + (c1 & 8191);
  const float4 a = *(const float4*)&eo[r0*D + d4];
  const float4 b = *(const float4*)&eo[r1*D + d4];
  float4 o; o.x = a.x+b.x; o.y = a.y+b.y; o.z = a.z+b.z; o.w = a.w+b.w;
  *(float4*)&out[(size_t)t*D + d4] = o;
}

extern "C" void kernel_launch(void* const* d_in, const int* in_sizes, int n_in,
                              void* d_out, int out_size, void* d_ws, size_t ws_size,
                              hipStream_t stream) {
  const float* x  = (const float*)d_in[0];
  const float* rw = (const float*)d_in[1];
  const float* gp = (const float*)d_in[2];
  const float* up = (const float*)d_in[3];
  const float* dp = (const float*)d_in[4];
  float* out = (float*)d_out;
  char* ws = (char*)d_ws;
  size_t off = 0;
  auto take = [&](size_t b) { char* p = ws + off; off += (b + 255) & ~(size_t)255; return p; };
  unsigned short* xb  = (unsigned short*)take((size_t)TOKENS * D * 2);        // 16.8 MB
  unsigned short* wgu = (unsigned short*)take((size_t)E * NGU * D * 2);       // 92.3 MB
  unsigned short* wdt = (unsigned short*)take((size_t)E * D * F * 2);         // 46.1 MB
  unsigned short* act = (unsigned short*)take((size_t)2 * TOKENS * F * 2);    // 92.3 MB
  unsigned short* ltok = (unsigned short*)take((size_t)E * TOKENS * 2);
  float* lw    = (float*)take((size_t)E * TOKENS * 4);
  int*   pcode = (int*)take((size_t)TOKENS * 2 * 4);
  int*   cnt   = (int*)take(64);
  int*   offs  = (int*)take(64);
  float* eo = (float*)wgu;   // 67 MB fp32 [16384][D]; wgu dead after pass1

  (void)hipFuncSetAttribute((const void*)k_pass1,
                            hipFuncAttributeMaxDynamicSharedMemorySize, 131072);
  hipMemsetAsync(cnt, 0, 8 * sizeof(int), stream);
  k_transpose_gu<<<dim3(F/64, D/64, E), 256, 0, stream>>>(gp, up, wgu);
  k_transpose<<<dim3(D/64, F/64, E), 256, 0, stream>>>(dp, wdt, F, D);   // -> [E][D][F]
  k_router<<<dim3(TOKENS/4), 256, 0, stream>>>(x, rw, xb, ltok, lw, pcode, cnt);
  k_scan<<<1, 64, 0, stream>>>(cnt, offs);
  k_pass1<<<dim3(NGU/256, TOKENS/256, E), 512, 131072, stream>>>(xb, wgu, ltok, cnt, offs, act);
  k_pass2<<<dim3(D/128, TOKENS/128, E), 256, 0, stream>>>(act, wdt, lw, cnt, offs, eo);
  k_combine<<<dim3(TOKENS), 256, 0, stream>>>(eo, pcode, offs, out);
}